// Round 23
// baseline (65.431 us; speedup 1.0000x reference)
//
#include <hip/hip_runtime.h>
#include <math.h>

#define NROWS 2048
#define HDIM 768
#define DDIM 128
#define FEAT 512
#define DCAP 2048
#define TSLOTS 8192

typedef __attribute__((ext_vector_type(8))) short bf16x8;
typedef __attribute__((ext_vector_type(4))) float f32x4;

// Online logsumexp-style merge: state (m, n, d) <- merge with (m2, n2, d2).
__device__ __forceinline__ void mergeState(float& m, float& n, float& d,
                                           float m2, float n2, float d2) {
  float M = fmaxf(m, m2);
  float s1 = (m >= M) ? 1.0f : __expf(m - M);
  float s2 = (m2 >= M) ? 1.0f : __expf(m2 - M);
  n = n * s1 + n2 * s2;
  d = d * s1 + d2 * s2;
  m = M;
}

__device__ __forceinline__ unsigned short bfhi(float x) {
  unsigned int u = __float_as_uint(x);
  return (unsigned short)((u + 0x7fffu + ((u >> 16) & 1u)) >> 16);
}

// ---------------------------------------------------------------------------
// k1m: fused convert+project GEMM. Reads E/Wmu/Wsg fp32, converts to bf16
// in-register while staging (dbuf LDS, 1 barrier per chunk). C[2048][256]
// partials over 4 K-splits. Block: M 64, N 128, K-split 192 (6 chunks).
// 256 threads (2x2 waves). Also clears tab/rowflag/dupcnt/gsum.
// ---------------------------------------------------------------------------
__global__ __launch_bounds__(256) void k1m(
    const float* __restrict__ E, const float* __restrict__ Wmu,
    const float* __restrict__ Wsg, float* __restrict__ Cpart,
    unsigned long long* __restrict__ tab, int* __restrict__ rowflag,
    int* __restrict__ dupcnt, float* __restrict__ gsum)
{
  __shared__ unsigned short lds[12288];   // 2 buf x 6144 (A 4KB + B 8KB)
  const int t = threadIdx.x;
  const int bid = blockIdx.x;

  // clears for downstream kernels
  if (t < 32) tab[bid * 32 + t] = 0ULL;
  if (t < 8)  rowflag[bid * 8 + t] = 0;
  if (bid == 0 && t == 0) {
    dupcnt[0] = 0;
    gsum[0] = 0.f; gsum[1] = 0.f; gsum[2] = 0.f;
  }

  const int mt = bid & 31, nt = (bid >> 5) & 1, ks = bid >> 6;
  const int i0 = mt * 64, kbase = ks * 192;
  const float* Wsrc = nt ? Wsg : Wmu;

  // staging geometry
  const int akg = t & 3, arow = t >> 2;        // A: lane -> (k-group, row)
  const int bcol = t & 127, bkh = t >> 7;      // B: lane -> (col, k-half)
  const int aw  = akg * 512 + arow * 8;                  // LDS ushort offs
  const int bw0 = 2048 + (bkh * 2) * 1024 + bcol * 8;
  const int bw1 = bw0 + 1024;

  float4 rA0, rA1; float rB[16];

  auto loadRegs = [&](int it) {
    const int ka = kbase + it * 32;
    const float* ep = E + (size_t)(i0 + arow) * HDIM + ka + akg * 8;
    rA0 = *reinterpret_cast<const float4*>(ep);
    rA1 = *reinterpret_cast<const float4*>(ep + 4);
    const float* wp = Wsrc + (size_t)(ka + bkh * 16) * DDIM + bcol;
    #pragma unroll
    for (int j = 0; j < 16; ++j) rB[j] = wp[(size_t)j * DDIM];
  };

  auto writeLds = [&](int buf) {
    unsigned short* lb = lds + buf * 6144;
    unsigned short ha[8];
    ha[0] = bfhi(fmaxf(rA0.x, 0.f)); ha[1] = bfhi(fmaxf(rA0.y, 0.f));
    ha[2] = bfhi(fmaxf(rA0.z, 0.f)); ha[3] = bfhi(fmaxf(rA0.w, 0.f));
    ha[4] = bfhi(fmaxf(rA1.x, 0.f)); ha[5] = bfhi(fmaxf(rA1.y, 0.f));
    ha[6] = bfhi(fmaxf(rA1.z, 0.f)); ha[7] = bfhi(fmaxf(rA1.w, 0.f));
    *reinterpret_cast<ushort4*>(lb + aw)     = make_ushort4(ha[0], ha[1], ha[2], ha[3]);
    *reinterpret_cast<ushort4*>(lb + aw + 4) = make_ushort4(ha[4], ha[5], ha[6], ha[7]);
    unsigned short hb[16];
    #pragma unroll
    for (int j = 0; j < 16; ++j) hb[j] = bfhi(rB[j]);
    *reinterpret_cast<ushort4*>(lb + bw0)     = make_ushort4(hb[0],  hb[1],  hb[2],  hb[3]);
    *reinterpret_cast<ushort4*>(lb + bw0 + 4) = make_ushort4(hb[4],  hb[5],  hb[6],  hb[7]);
    *reinterpret_cast<ushort4*>(lb + bw1)     = make_ushort4(hb[8],  hb[9],  hb[10], hb[11]);
    *reinterpret_cast<ushort4*>(lb + bw1 + 4) = make_ushort4(hb[12], hb[13], hb[14], hb[15]);
  };

  f32x4 acc[2][4];
  #pragma unroll
  for (int a = 0; a < 2; ++a)
    #pragma unroll
    for (int b = 0; b < 4; ++b) {
      acc[a][b][0] = 0.f; acc[a][b][1] = 0.f; acc[a][b][2] = 0.f; acc[a][b][3] = 0.f;
    }

  const int wid = t >> 6, lane = t & 63;
  const int wr = wid >> 1, wc = wid & 1;
  const int gq = lane >> 4, c0 = lane & 15;

  loadRegs(0);
  writeLds(0);
  loadRegs(1);
  __syncthreads();

  for (int it = 0; it < 6; ++it) {
    {
      const unsigned short* lb = lds + (it & 1) * 6144;
      bf16x8 ah[2], bh[4];
      #pragma unroll
      for (int fa = 0; fa < 2; ++fa) {
        const int ia = gq * 512 + (wr * 32 + fa * 16 + c0) * 8;
        ah[fa] = *reinterpret_cast<const bf16x8*>(lb + ia);
      }
      #pragma unroll
      for (int fb = 0; fb < 4; ++fb) {
        const int ib = 2048 + gq * 1024 + (wc * 64 + fb * 16 + c0) * 8;
        bh[fb] = *reinterpret_cast<const bf16x8*>(lb + ib);
      }
      #pragma unroll
      for (int fa = 0; fa < 2; ++fa)
        #pragma unroll
        for (int fb = 0; fb < 4; ++fb)
          acc[fa][fb] = __builtin_amdgcn_mfma_f32_16x16x32_bf16(
              ah[fa], bh[fb], acc[fa][fb], 0, 0, 0);
    }
    if (it < 5) {
      writeLds((it + 1) & 1);        // buf consumed at it-1; safe
      if (it < 4) loadRegs(it + 2);
    }
    __syncthreads();
  }

  const int n0 = nt * 128;
  #pragma unroll
  for (int fa = 0; fa < 2; ++fa)
    #pragma unroll
    for (int fb = 0; fb < 4; ++fb)
      #pragma unroll
      for (int r = 0; r < 4; ++r) {
        const int row = i0 + wr * 32 + fa * 16 + gq * 4 + r;
        const int col = n0 + wc * 64 + fb * 16 + c0;
        Cpart[((size_t)ks * NROWS + row) * 256 + col] = acc[fa][fb][r];
      }
}

// ---------------------------------------------------------------------------
// k1e: 16 rows per block. Reduce 4 K-split partials -> mu/sigma -> single-
// bf16 features staged in LDS -> Ftl in fragment-tiled order via contiguous
// 16B stores. Also q + dup hash.
// Ftl[g][kb][lane][8]: lane = gq*16+c0 holds (row g*16+c0, k = kb*32+gq*8+j).
// ---------------------------------------------------------------------------
__global__ __launch_bounds__(256) void k1e(
    const float* __restrict__ Cpart, const float* __restrict__ bmu,
    const float* __restrict__ bsg,
    unsigned short* __restrict__ Ftl,
    float* __restrict__ qout, unsigned long long* __restrict__ tab,
    int* __restrict__ rowflag, int* __restrict__ dupcnt,
    int2* __restrict__ duplist)
{
  __shared__ unsigned short fbuf[16][520];   // padded rows (bank spread)
  const int t = threadIdx.x;
  const int row16 = t >> 4, cw = t & 15, c8 = cw * 8;
  const int g = blockIdx.x;
  const int rg = g * 16 + row16;

  float vm[8], vs[8];
  #pragma unroll
  for (int j = 0; j < 8; ++j) { vm[j] = 0.f; vs[j] = 0.f; }
  #pragma unroll
  for (int ks = 0; ks < 4; ++ks) {
    const float* src = &Cpart[((size_t)ks * NROWS + rg) * 256];
    float4 m0 = *reinterpret_cast<const float4*>(src + c8);
    float4 m1 = *reinterpret_cast<const float4*>(src + c8 + 4);
    float4 s0 = *reinterpret_cast<const float4*>(src + 128 + c8);
    float4 s1 = *reinterpret_cast<const float4*>(src + 128 + c8 + 4);
    vm[0] += m0.x; vm[1] += m0.y; vm[2] += m0.z; vm[3] += m0.w;
    vm[4] += m1.x; vm[5] += m1.y; vm[6] += m1.z; vm[7] += m1.w;
    vs[0] += s0.x; vs[1] += s0.y; vs[2] += s0.z; vs[3] += s0.w;
    vs[4] += s1.x; vs[5] += s1.y; vs[6] += s1.z; vs[7] += s1.w;
  }

  float q = 0.f;
  unsigned int hx = 0u, hs2 = 0u;
  unsigned short o1[8], o2[8], o3[8], o4[8];
  #pragma unroll
  for (int j = 0; j < 8; ++j) {
    const int col = c8 + j;
    float z = vs[j] + bsg[col];
    float s = (z > 0.f ? z + 1.0f : __expf(z)) + 1e-14f;
    float mu = vm[j] + bmu[col];
    float inv = 1.0f / s;
    o1[j] = bfhi(inv);
    o2[j] = bfhi(s + mu * mu);
    o3[j] = bfhi(-2.0f * mu * inv);
    o4[j] = bfhi(mu);
    q += mu * mu * inv;
    unsigned int b = __float_as_uint(mu);
    if (b == 0x80000000u) b = 0u;
    unsigned int hm = (b ^ ((unsigned int)col * 0x9E3779B9u)) * 0x85EBCA6Bu;
    hm ^= hm >> 13;
    hx ^= hm;
    hs2 += hm * 0xC2B2AE35u;
  }
  *reinterpret_cast<ushort4*>(&fbuf[row16][      c8])     = make_ushort4(o1[0], o1[1], o1[2], o1[3]);
  *reinterpret_cast<ushort4*>(&fbuf[row16][      c8 + 4]) = make_ushort4(o1[4], o1[5], o1[6], o1[7]);
  *reinterpret_cast<ushort4*>(&fbuf[row16][128 + c8])     = make_ushort4(o2[0], o2[1], o2[2], o2[3]);
  *reinterpret_cast<ushort4*>(&fbuf[row16][128 + c8 + 4]) = make_ushort4(o2[4], o2[5], o2[6], o2[7]);
  *reinterpret_cast<ushort4*>(&fbuf[row16][256 + c8])     = make_ushort4(o3[0], o3[1], o3[2], o3[3]);
  *reinterpret_cast<ushort4*>(&fbuf[row16][256 + c8 + 4]) = make_ushort4(o3[4], o3[5], o3[6], o3[7]);
  *reinterpret_cast<ushort4*>(&fbuf[row16][384 + c8])     = make_ushort4(o4[0], o4[1], o4[2], o4[3]);
  *reinterpret_cast<ushort4*>(&fbuf[row16][384 + c8 + 4]) = make_ushort4(o4[4], o4[5], o4[6], o4[7]);

  // 16-lane (per-row) reductions
  #pragma unroll
  for (int o = 8; o; o >>= 1) q += __shfl_xor(q, o, 16);
  #pragma unroll
  for (int o = 1; o < 16; o <<= 1) {
    hx  ^= (unsigned int)__shfl_xor((int)hx, o, 16);
    hs2 += (unsigned int)__shfl_xor((int)hs2, o, 16);
  }
  if (cw == 0) {
    qout[rg] = q;
    unsigned long long key = (((unsigned long long)hx << 32) | hs2) & ~0xFFFULL;
    if (key == 0ULL) key = 0x123456789000ULL;
    const unsigned long long me = key | (unsigned long long)(rg + 1);
    unsigned int h = (hx ^ (hs2 * 0x9E3779B9u)) & (TSLOTS - 1);
    for (;;) {
      unsigned long long old = atomicCAS(&tab[h], 0ULL, me);
      if (old == 0ULL) break;
      if ((old & ~0xFFFULL) == key) {
        int r2 = (int)(old & 0xFFFULL) - 1;
        rowflag[rg] = 1; rowflag[r2] = 1;
        int e = atomicAdd(dupcnt, 1);
        if (e < DCAP) duplist[e] = make_int2(min(rg, r2), max(rg, r2));
      }
      h = (h + 1u) & (TSLOTS - 1);
    }
  }
  __syncthreads();

  // contiguous fragment-tiled stores: f = u*256+t -> kb = f>>6, ln = f&63
  #pragma unroll
  for (int u = 0; u < 4; ++u) {
    const int f = u * 256 + t;
    const int kb = f >> 6, ln = f & 63;
    const int gq2 = ln >> 4, cc = ln & 15;
    uint4 v = *reinterpret_cast<const uint4*>(&fbuf[cc][kb * 32 + gq2 * 8]);
    *reinterpret_cast<uint4*>(&Ftl[((size_t)(g * 16 + kb)) * 512 + ln * 8]) = v;
  }
}

// ---------------------------------------------------------------------------
// K2: single-bf16 MFMA all-pairs (K=512). Tile 128x64, 512 thr = 8 waves
// (4i x 2j), wave 32x32. B panel 64 KB in LDS (staged once). A panel staged
// via k1m-style reg->LDS dbuf: 4 super-chunks of 32 KB (4 kb each), write
// s+1 / load s+2 interleaved with compute(s); 8 barriers total. All
// fragment reads are conflict-free ds_read_b128; zero redundant global A
// loads. B feature swap = kb^4. 2D XCD map (4bi x 16bj per XCD).
// ---------------------------------------------------------------------------
__global__ __launch_bounds__(512, 2) void k2_mfma(
    const unsigned short* __restrict__ Ftl,
    const float* __restrict__ qv, const int* __restrict__ labels,
    const int* __restrict__ msk, const int* __restrict__ rowflag,
    const int* __restrict__ dupcnt, const int2* __restrict__ duplist,
    float4* __restrict__ ipart)
{
  __shared__ unsigned short Blds[32768];          // 64 KB
  __shared__ unsigned short Alds[32768];          // 2 buf x 32 KB
  const int t = threadIdx.x;
  const int orig = blockIdx.x;
  const int xcd = orig & 7, idx = orig >> 3;      // 2D XCD map: 4bi x 16bj
  const int bi = (xcd >> 1) * 4 + (idx >> 4);     // 0..15
  const int bj = (xcd & 1) * 16 + (idx & 15);     // 0..31
  const int i0 = bi * 128, j0 = bj * 64;
  const int wid = t >> 6, lane = t & 63;
  const int wr = wid >> 1, wc = wid & 1;          // 4i x 2j waves, wave 32x32
  const int gq = lane >> 4, c0 = lane & 15;

  // ---- stage B panel once: contiguous 64 KB copy ----
  {
    const unsigned short* Bsrc = Ftl + (size_t)bj * 32768;
    #pragma unroll
    for (int u = 0; u < 8; ++u) {
      const int slot = u * 512 + t;
      uint4 v = *reinterpret_cast<const uint4*>(Bsrc + slot * 8);
      *reinterpret_cast<uint4*>(Blds + slot * 8) = v;
    }
  }

  // ---- A staging geometry: super-chunk s = 4 kb = 32 fragments of 1KB ----
  // thread t handles fragments fi = u*8 + (t>>6), u=0..3; lane offset 16B.
  const unsigned short* bl = Blds + lane * 8;     // per-lane B base
  const int hb0 = wc * 2;                         // B col-group within block
  uint4 sreg[4];

  auto stageRegs = [&](int s) {
    #pragma unroll
    for (int u = 0; u < 4; ++u) {
      const int fi = u * 8 + wid;
      const int g = fi >> 2, kbo = fi & 3;
      sreg[u] = *reinterpret_cast<const uint4*>(
          Ftl + ((size_t)((bi * 8 + g) * 16 + 4 * s + kbo)) * 512 + lane * 8);
    }
  };
  auto writeA = [&](int s) {
    unsigned short* ab = Alds + (s & 1) * 16384;
    #pragma unroll
    for (int u = 0; u < 4; ++u) {
      const int fi = u * 8 + wid;
      *reinterpret_cast<uint4*>(ab + fi * 512 + lane * 8) = sreg[u];
    }
  };

  f32x4 acc[2][2];
  #pragma unroll
  for (int a = 0; a < 2; ++a)
    #pragma unroll
    for (int b = 0; b < 2; ++b) {
      acc[a][b][0] = 0.f; acc[a][b][1] = 0.f; acc[a][b][2] = 0.f; acc[a][b][3] = 0.f;
    }

  stageRegs(0);
  writeA(0);
  stageRegs(1);
  __syncthreads();            // B panel + A buf0 ready

  for (int s = 0; s < 4; ++s) {
    {
      const unsigned short* ab = Alds + (s & 1) * 16384;
      #pragma unroll
      for (int kbo = 0; kbo < 4; ++kbo) {
        const int kb = 4 * s + kbo;
        const int kbb = kb ^ 4;
        bf16x8 A0 = *reinterpret_cast<const bf16x8*>(
            ab + ((wr * 2 + 0) * 4 + kbo) * 512 + lane * 8);
        bf16x8 A1 = *reinterpret_cast<const bf16x8*>(
            ab + ((wr * 2 + 1) * 4 + kbo) * 512 + lane * 8);
        bf16x8 B0 = *reinterpret_cast<const bf16x8*>(bl + ((hb0    ) * 16 + kbb) * 512);
        bf16x8 B1 = *reinterpret_cast<const bf16x8*>(bl + ((hb0 + 1) * 16 + kbb) * 512);
        acc[0][0] = __builtin_amdgcn_mfma_f32_16x16x32_bf16(A0, B0, acc[0][0], 0, 0, 0);
        acc[0][1] = __builtin_amdgcn_mfma_f32_16x16x32_bf16(A0, B1, acc[0][1], 0, 0, 0);
        acc[1][0] = __builtin_amdgcn_mfma_f32_16x16x32_bf16(A1, B0, acc[1][0], 0, 0, 0);
        acc[1][1] = __builtin_amdgcn_mfma_f32_16x16x32_bf16(A1, B1, acc[1][1], 0, 0, 0);
      }
    }
    if (s < 3) {
      writeA(s + 1);          // buf consumed at s-1; safe
      if (s < 2) stageRegs(s + 2);
    }
    __syncthreads();
  }

  // ---- epilogue: NT-Xent online merge per output row ----
  const int ndup = min(dupcnt[0], DCAP);
  int ljv[2]; float qjv[2]; int fjv[2]; int gjv[2];
  #pragma unroll
  for (int fb = 0; fb < 2; ++fb) {
    const int gj = j0 + wc * 32 + fb * 16 + c0;
    const int lab = labels[gj];
    ljv[fb] = (msk[gj] == 1 && lab >= 0) ? lab : -1;
    qjv[fb] = qv[gj];
    fjv[fb] = rowflag[gj];
    gjv[fb] = gj;
  }
  #pragma unroll
  for (int fa = 0; fa < 2; ++fa) {
    const int ibase = i0 + wr * 32 + fa * 16 + gq * 4;
    int li4[4], mi4[4], fi4[4]; float qi4[4];
    *reinterpret_cast<int4*>(li4)   = *reinterpret_cast<const int4*>(labels + ibase);
    *reinterpret_cast<int4*>(mi4)   = *reinterpret_cast<const int4*>(msk + ibase);
    *reinterpret_cast<int4*>(fi4)   = *reinterpret_cast<const int4*>(rowflag + ibase);
    *reinterpret_cast<float4*>(qi4) = *reinterpret_cast<const float4*>(qv + ibase);
    #pragma unroll
    for (int r = 0; r < 4; ++r) {
      const int gi = ibase + r;
      const int li = (mi4[r] == 1 && li4[r] >= 0) ? li4[r] : -1;
      float m = -INFINITY, n = 0.f, d = 0.f, c = 0.f;
      if (li >= 0) {
        #pragma unroll
        for (int fb = 0; fb < 2; ++fb) {
          const int lj = ljv[fb];
          bool inc = (lj >= 0) && (gi != gjv[fb]);
          if (inc && fi4[r] && fjv[fb]) {
            int plo = min(gi, gjv[fb]), phi = max(gi, gjv[fb]);
            for (int e = 0; e < ndup; ++e) {
              int2 p = duplist[e];
              if (p.x == plo && p.y == phi) { inc = false; break; }
            }
          }
          if (inc) {
            float S = acc[fa][fb][r];
            float l = 64.0f - 0.25f * (qi4[r] + qjv[fb] + S);
            float w = (li == lj) ? 1.0f : 0.0f;
            mergeState(m, n, d, l, w, 1.0f);
            c += w;
          }
        }
      }
      #pragma unroll
      for (int o = 1; o < 16; o <<= 1) {
        float m2 = __shfl_xor(m, o);
        float n2 = __shfl_xor(n, o);
        float d2 = __shfl_xor(d, o);
        float c2 = __shfl_xor(c, o);
        mergeState(m, n, d, m2, n2, d2);
        c += c2;
      }
      if (c0 == 0)
        ipart[(size_t)(bj * 2 + wc) * NROWS + gi] = make_float4(m, n, d, c);
    }
  }
}

// ---------------------------------------------------------------------------
// k3: merge 64 j-slices per row, per-block sums, then device-scope atomic
// accumulate + ticket; last of 8 blocks writes the final scalar.
// gsum[0]=L, gsum[1]=C, gsum[2]=ticket (all cleared by k1m).
// ---------------------------------------------------------------------------
__global__ __launch_bounds__(256) void k3(const float4* __restrict__ ipart,
                                          float* __restrict__ gsum,
                                          float* __restrict__ out)
{
  const int r = blockIdx.x * 256 + threadIdx.x;
  float m = -INFINITY, n = 0.f, d = 0.f, c = 0.f;
  #pragma unroll 8
  for (int js = 0; js < 64; ++js) {
    float4 p = ipart[(size_t)js * NROWS + r];
    mergeState(m, n, d, p.x, p.y, p.z);
    c += p.w;
  }
  float lf = 0.f, ns = 0.f;
  if (c > 0.f) {
    lf = log2f(d) - log2f(n) + log2f(c);
    ns = 1.f;
  }
  #pragma unroll
  for (int o = 32; o; o >>= 1) {
    lf += __shfl_down(lf, o);
    ns += __shfl_down(ns, o);
  }
  __shared__ float sl[4], sn[4];
  const int wid = threadIdx.x >> 6;
  if ((threadIdx.x & 63) == 0) { sl[wid] = lf; sn[wid] = ns; }
  __syncthreads();
  if (threadIdx.x == 0) {
    float L = sl[0] + sl[1] + sl[2] + sl[3];
    float C = sn[0] + sn[1] + sn[2] + sn[3];
    atomicAdd(&gsum[0], L);
    atomicAdd(&gsum[1], C);
    __threadfence();
    unsigned int tk = atomicAdd(reinterpret_cast<unsigned int*>(gsum + 2), 1u);
    if (tk == 7u) {
      float Lt = atomicAdd(&gsum[0], 0.f);
      float Ct = atomicAdd(&gsum[1], 0.f);
      out[0] = Lt / fmaxf(Ct, 1.0f);
    }
  }
}

// ---------------------------------------------------------------------------
extern "C" void kernel_launch(void* const* d_in, const int* in_sizes, int n_in,
                              void* d_out, int out_size, void* d_ws, size_t ws_size,
                              hipStream_t stream) {
  const float* E   = (const float*)d_in[0];
  const int*   tid = (const int*)d_in[1];
  const int*   msk = (const int*)d_in[2];
  const float* Wmu = (const float*)d_in[3];
  const float* bmu = (const float*)d_in[4];
  const float* Wsg = (const float*)d_in[5];
  const float* bsg = (const float*)d_in[6];

  unsigned char* w = (unsigned char*)d_ws;
  unsigned short* Ftl  = (unsigned short*)w;  w += (size_t)NROWS * FEAT * 2;   // 2 MB
  float* Cpart         = (float*)w;           w += (size_t)4 * NROWS * 256 * 4; // 8 MB
  float* qv            = (float*)w;           w += (size_t)NROWS * 4;
  unsigned long long* tab = (unsigned long long*)w; w += (size_t)TSLOTS * 8;   // 64 KB
  int* rowflag         = (int*)w;             w += (size_t)NROWS * 4;
  int* dupcnt          = (int*)w;             w += 256;
  float* gsum          = (float*)w;           w += 256;
  int2* duplist        = (int2*)w;            w += (size_t)DCAP * 8;
  float4* ipart        = (float4*)w;          w += (size_t)64 * NROWS * 16;    // 2 MB

  k1m<<<256, 256, 0, stream>>>(E, Wmu, Wsg, Cpart, tab, rowflag, dupcnt, gsum);
  k1e<<<128, 256, 0, stream>>>(Cpart, bmu, bsg, Ftl, qv,
                               tab, rowflag, dupcnt, duplist);
  k2_mfma<<<512, 512, 0, stream>>>(Ftl, qv, tid, msk, rowflag,
                                   dupcnt, duplist, ipart);
  k3<<<8, 256, 0, stream>>>(ipart, gsum, (float*)d_out);
}

// Round 24
// 43.940 us; speedup vs baseline: 1.4891x; 1.4891x over previous
//
#include <hip/hip_runtime.h>
#include <math.h>

#define NROWS 2048
#define HDIM 768
#define DDIM 128
#define FEAT 512
#define DCAP 2048
#define TSLOTS 8192

typedef __attribute__((ext_vector_type(8))) short bf16x8;
typedef __attribute__((ext_vector_type(4))) float f32x4;

// Online logsumexp-style merge: state (m, n, d) <- merge with (m2, n2, d2).
__device__ __forceinline__ void mergeState(float& m, float& n, float& d,
                                           float m2, float n2, float d2) {
  float M = fmaxf(m, m2);
  float s1 = (m >= M) ? 1.0f : __expf(m - M);
  float s2 = (m2 >= M) ? 1.0f : __expf(m2 - M);
  n = n * s1 + n2 * s2;
  d = d * s1 + d2 * s2;
  m = M;
}

__device__ __forceinline__ unsigned short bfhi(float x) {
  unsigned int u = __float_as_uint(x);
  return (unsigned short)((u + 0x7fffu + ((u >> 16) & 1u)) >> 16);
}

// ---------------------------------------------------------------------------
// k1m: fused convert+project GEMM. Reads E/Wmu/Wsg fp32, converts to bf16
// in-register while staging (dbuf LDS, 1 barrier per chunk). C[2048][256]
// partials over 4 K-splits. Block: M 64, N 128, K-split 192 (6 chunks).
// 256 threads (2x2 waves). Also clears tab/rowflag/dupcnt/gsum.
// ---------------------------------------------------------------------------
__global__ __launch_bounds__(256) void k1m(
    const float* __restrict__ E, const float* __restrict__ Wmu,
    const float* __restrict__ Wsg, float* __restrict__ Cpart,
    unsigned long long* __restrict__ tab, int* __restrict__ rowflag,
    int* __restrict__ dupcnt, float* __restrict__ gsum)
{
  __shared__ unsigned short lds[12288];   // 2 buf x 6144 (A 4KB + B 8KB)
  const int t = threadIdx.x;
  const int bid = blockIdx.x;

  // clears for downstream kernels
  if (t < 32) tab[bid * 32 + t] = 0ULL;
  if (t < 8)  rowflag[bid * 8 + t] = 0;
  if (bid == 0 && t == 0) {
    dupcnt[0] = 0;
    gsum[0] = 0.f; gsum[1] = 0.f; gsum[2] = 0.f;
  }

  const int mt = bid & 31, nt = (bid >> 5) & 1, ks = bid >> 6;
  const int i0 = mt * 64, kbase = ks * 192;
  const float* Wsrc = nt ? Wsg : Wmu;

  // staging geometry
  const int akg = t & 3, arow = t >> 2;        // A: lane -> (k-group, row)
  const int bcol = t & 127, bkh = t >> 7;      // B: lane -> (col, k-half)
  const int aw  = akg * 512 + arow * 8;                  // LDS ushort offs
  const int bw0 = 2048 + (bkh * 2) * 1024 + bcol * 8;
  const int bw1 = bw0 + 1024;

  float4 rA0, rA1; float rB[16];

  auto loadRegs = [&](int it) {
    const int ka = kbase + it * 32;
    const float* ep = E + (size_t)(i0 + arow) * HDIM + ka + akg * 8;
    rA0 = *reinterpret_cast<const float4*>(ep);
    rA1 = *reinterpret_cast<const float4*>(ep + 4);
    const float* wp = Wsrc + (size_t)(ka + bkh * 16) * DDIM + bcol;
    #pragma unroll
    for (int j = 0; j < 16; ++j) rB[j] = wp[(size_t)j * DDIM];
  };

  auto writeLds = [&](int buf) {
    unsigned short* lb = lds + buf * 6144;
    unsigned short ha[8];
    ha[0] = bfhi(fmaxf(rA0.x, 0.f)); ha[1] = bfhi(fmaxf(rA0.y, 0.f));
    ha[2] = bfhi(fmaxf(rA0.z, 0.f)); ha[3] = bfhi(fmaxf(rA0.w, 0.f));
    ha[4] = bfhi(fmaxf(rA1.x, 0.f)); ha[5] = bfhi(fmaxf(rA1.y, 0.f));
    ha[6] = bfhi(fmaxf(rA1.z, 0.f)); ha[7] = bfhi(fmaxf(rA1.w, 0.f));
    *reinterpret_cast<ushort4*>(lb + aw)     = make_ushort4(ha[0], ha[1], ha[2], ha[3]);
    *reinterpret_cast<ushort4*>(lb + aw + 4) = make_ushort4(ha[4], ha[5], ha[6], ha[7]);
    unsigned short hb[16];
    #pragma unroll
    for (int j = 0; j < 16; ++j) hb[j] = bfhi(rB[j]);
    *reinterpret_cast<ushort4*>(lb + bw0)     = make_ushort4(hb[0],  hb[1],  hb[2],  hb[3]);
    *reinterpret_cast<ushort4*>(lb + bw0 + 4) = make_ushort4(hb[4],  hb[5],  hb[6],  hb[7]);
    *reinterpret_cast<ushort4*>(lb + bw1)     = make_ushort4(hb[8],  hb[9],  hb[10], hb[11]);
    *reinterpret_cast<ushort4*>(lb + bw1 + 4) = make_ushort4(hb[12], hb[13], hb[14], hb[15]);
  };

  f32x4 acc[2][4];
  #pragma unroll
  for (int a = 0; a < 2; ++a)
    #pragma unroll
    for (int b = 0; b < 4; ++b) {
      acc[a][b][0] = 0.f; acc[a][b][1] = 0.f; acc[a][b][2] = 0.f; acc[a][b][3] = 0.f;
    }

  const int wid = t >> 6, lane = t & 63;
  const int wr = wid >> 1, wc = wid & 1;
  const int gq = lane >> 4, c0 = lane & 15;

  loadRegs(0);
  writeLds(0);
  loadRegs(1);
  __syncthreads();

  for (int it = 0; it < 6; ++it) {
    {
      const unsigned short* lb = lds + (it & 1) * 6144;
      bf16x8 ah[2], bh[4];
      #pragma unroll
      for (int fa = 0; fa < 2; ++fa) {
        const int ia = gq * 512 + (wr * 32 + fa * 16 + c0) * 8;
        ah[fa] = *reinterpret_cast<const bf16x8*>(lb + ia);
      }
      #pragma unroll
      for (int fb = 0; fb < 4; ++fb) {
        const int ib = 2048 + gq * 1024 + (wc * 64 + fb * 16 + c0) * 8;
        bh[fb] = *reinterpret_cast<const bf16x8*>(lb + ib);
      }
      #pragma unroll
      for (int fa = 0; fa < 2; ++fa)
        #pragma unroll
        for (int fb = 0; fb < 4; ++fb)
          acc[fa][fb] = __builtin_amdgcn_mfma_f32_16x16x32_bf16(
              ah[fa], bh[fb], acc[fa][fb], 0, 0, 0);
    }
    if (it < 5) {
      writeLds((it + 1) & 1);        // buf consumed at it-1; safe
      if (it < 4) loadRegs(it + 2);
    }
    __syncthreads();
  }

  const int n0 = nt * 128;
  #pragma unroll
  for (int fa = 0; fa < 2; ++fa)
    #pragma unroll
    for (int fb = 0; fb < 4; ++fb)
      #pragma unroll
      for (int r = 0; r < 4; ++r) {
        const int row = i0 + wr * 32 + fa * 16 + gq * 4 + r;
        const int col = n0 + wc * 64 + fb * 16 + c0;
        Cpart[((size_t)ks * NROWS + row) * 256 + col] = acc[fa][fb][r];
      }
}

// ---------------------------------------------------------------------------
// k1e: 16 rows per block. Reduce 4 K-split partials -> mu/sigma -> single-
// bf16 features staged in LDS -> Ftl in fragment-tiled order via contiguous
// 16B stores. Also q + dup hash.
// Ftl[g][kb][lane][8]: lane = gq*16+c0 holds (row g*16+c0, k = kb*32+gq*8+j).
// ---------------------------------------------------------------------------
__global__ __launch_bounds__(256) void k1e(
    const float* __restrict__ Cpart, const float* __restrict__ bmu,
    const float* __restrict__ bsg,
    unsigned short* __restrict__ Ftl,
    float* __restrict__ qout, unsigned long long* __restrict__ tab,
    int* __restrict__ rowflag, int* __restrict__ dupcnt,
    int2* __restrict__ duplist)
{
  __shared__ unsigned short fbuf[16][520];   // padded rows (bank spread)
  const int t = threadIdx.x;
  const int row16 = t >> 4, cw = t & 15, c8 = cw * 8;
  const int g = blockIdx.x;
  const int rg = g * 16 + row16;

  float vm[8], vs[8];
  #pragma unroll
  for (int j = 0; j < 8; ++j) { vm[j] = 0.f; vs[j] = 0.f; }
  #pragma unroll
  for (int ks = 0; ks < 4; ++ks) {
    const float* src = &Cpart[((size_t)ks * NROWS + rg) * 256];
    float4 m0 = *reinterpret_cast<const float4*>(src + c8);
    float4 m1 = *reinterpret_cast<const float4*>(src + c8 + 4);
    float4 s0 = *reinterpret_cast<const float4*>(src + 128 + c8);
    float4 s1 = *reinterpret_cast<const float4*>(src + 128 + c8 + 4);
    vm[0] += m0.x; vm[1] += m0.y; vm[2] += m0.z; vm[3] += m0.w;
    vm[4] += m1.x; vm[5] += m1.y; vm[6] += m1.z; vm[7] += m1.w;
    vs[0] += s0.x; vs[1] += s0.y; vs[2] += s0.z; vs[3] += s0.w;
    vs[4] += s1.x; vs[5] += s1.y; vs[6] += s1.z; vs[7] += s1.w;
  }

  float q = 0.f;
  unsigned int hx = 0u, hs2 = 0u;
  unsigned short o1[8], o2[8], o3[8], o4[8];
  #pragma unroll
  for (int j = 0; j < 8; ++j) {
    const int col = c8 + j;
    float z = vs[j] + bsg[col];
    float s = (z > 0.f ? z + 1.0f : __expf(z)) + 1e-14f;
    float mu = vm[j] + bmu[col];
    float inv = 1.0f / s;
    o1[j] = bfhi(inv);
    o2[j] = bfhi(s + mu * mu);
    o3[j] = bfhi(-2.0f * mu * inv);
    o4[j] = bfhi(mu);
    q += mu * mu * inv;
    unsigned int b = __float_as_uint(mu);
    if (b == 0x80000000u) b = 0u;
    unsigned int hm = (b ^ ((unsigned int)col * 0x9E3779B9u)) * 0x85EBCA6Bu;
    hm ^= hm >> 13;
    hx ^= hm;
    hs2 += hm * 0xC2B2AE35u;
  }
  *reinterpret_cast<ushort4*>(&fbuf[row16][      c8])     = make_ushort4(o1[0], o1[1], o1[2], o1[3]);
  *reinterpret_cast<ushort4*>(&fbuf[row16][      c8 + 4]) = make_ushort4(o1[4], o1[5], o1[6], o1[7]);
  *reinterpret_cast<ushort4*>(&fbuf[row16][128 + c8])     = make_ushort4(o2[0], o2[1], o2[2], o2[3]);
  *reinterpret_cast<ushort4*>(&fbuf[row16][128 + c8 + 4]) = make_ushort4(o2[4], o2[5], o2[6], o2[7]);
  *reinterpret_cast<ushort4*>(&fbuf[row16][256 + c8])     = make_ushort4(o3[0], o3[1], o3[2], o3[3]);
  *reinterpret_cast<ushort4*>(&fbuf[row16][256 + c8 + 4]) = make_ushort4(o3[4], o3[5], o3[6], o3[7]);
  *reinterpret_cast<ushort4*>(&fbuf[row16][384 + c8])     = make_ushort4(o4[0], o4[1], o4[2], o4[3]);
  *reinterpret_cast<ushort4*>(&fbuf[row16][384 + c8 + 4]) = make_ushort4(o4[4], o4[5], o4[6], o4[7]);

  // 16-lane (per-row) reductions
  #pragma unroll
  for (int o = 8; o; o >>= 1) q += __shfl_xor(q, o, 16);
  #pragma unroll
  for (int o = 1; o < 16; o <<= 1) {
    hx  ^= (unsigned int)__shfl_xor((int)hx, o, 16);
    hs2 += (unsigned int)__shfl_xor((int)hs2, o, 16);
  }
  if (cw == 0) {
    qout[rg] = q;
    unsigned long long key = (((unsigned long long)hx << 32) | hs2) & ~0xFFFULL;
    if (key == 0ULL) key = 0x123456789000ULL;
    const unsigned long long me = key | (unsigned long long)(rg + 1);
    unsigned int h = (hx ^ (hs2 * 0x9E3779B9u)) & (TSLOTS - 1);
    for (;;) {
      unsigned long long old = atomicCAS(&tab[h], 0ULL, me);
      if (old == 0ULL) break;
      if ((old & ~0xFFFULL) == key) {
        int r2 = (int)(old & 0xFFFULL) - 1;
        rowflag[rg] = 1; rowflag[r2] = 1;
        int e = atomicAdd(dupcnt, 1);
        if (e < DCAP) duplist[e] = make_int2(min(rg, r2), max(rg, r2));
      }
      h = (h + 1u) & (TSLOTS - 1);
    }
  }
  __syncthreads();

  // contiguous fragment-tiled stores: f = u*256+t -> kb = f>>6, ln = f&63
  #pragma unroll
  for (int u = 0; u < 4; ++u) {
    const int f = u * 256 + t;
    const int kb = f >> 6, ln = f & 63;
    const int gq2 = ln >> 4, cc = ln & 15;
    uint4 v = *reinterpret_cast<const uint4*>(&fbuf[cc][kb * 32 + gq2 * 8]);
    *reinterpret_cast<uint4*>(&Ftl[((size_t)(g * 16 + kb)) * 512 + ln * 8]) = v;
  }
}

// ---------------------------------------------------------------------------
// K2: single-bf16 MFMA all-pairs (K=512), hybrid placement. Tile 128x64:
// B panel 64 KB in LDS -> TWO blocks/CU (cross-block latency hiding, m114).
// 512 thr = 8 waves (4i x 2j), wave 32x32, depth-2 Abuf[3] A prefetch from
// global (fragment-tiled 1KB wave loads), B via conflict-free ds_read_b128.
// B feature swap = kb^4. 2D XCD map (4bi x 16bj per XCD).
// ---------------------------------------------------------------------------
__global__ __launch_bounds__(512, 2) void k2_mfma(
    const unsigned short* __restrict__ Ftl,
    const float* __restrict__ qv, const int* __restrict__ labels,
    const int* __restrict__ msk, const int* __restrict__ rowflag,
    const int* __restrict__ dupcnt, const int2* __restrict__ duplist,
    float4* __restrict__ ipart)
{
  __shared__ unsigned short Blds[32768];          // 64 KB
  const int t = threadIdx.x;
  const int orig = blockIdx.x;
  const int xcd = orig & 7, idx = orig >> 3;      // 2D XCD map: 4bi x 16bj
  const int bi = (xcd >> 1) * 4 + (idx >> 4);     // 0..15
  const int bj = (xcd & 1) * 16 + (idx & 15);     // 0..31
  const int i0 = bi * 128, j0 = bj * 64;
  const int wid = t >> 6, lane = t & 63;
  const int wr = wid >> 1, wc = wid & 1;          // 4i x 2j waves, wave 32x32
  const int gq = lane >> 4, c0 = lane & 15;

  // ---- stage B panel once: contiguous 64 KB copy ----
  {
    const unsigned short* Bsrc = Ftl + (size_t)bj * 32768;
    #pragma unroll
    for (int u = 0; u < 8; ++u) {
      const int slot = u * 512 + t;
      uint4 v = *reinterpret_cast<const uint4*>(Bsrc + slot * 8);
      *reinterpret_cast<uint4*>(Blds + slot * 8) = v;
    }
  }
  __syncthreads();

  const int ga0 = bi * 8 + wr * 2;                // A row-group of fa=0
  const unsigned short* fl = Ftl + lane * 8;      // per-lane A base
  const unsigned short* bl = Blds + lane * 8;     // per-lane B base (LDS)
  const int hb0 = wc * 2;                         // B col-group within block

  f32x4 acc[2][2];
  #pragma unroll
  for (int a = 0; a < 2; ++a)
    #pragma unroll
    for (int b = 0; b < 2; ++b) {
      acc[a][b][0] = 0.f; acc[a][b][1] = 0.f; acc[a][b][2] = 0.f; acc[a][b][3] = 0.f;
    }

  bf16x8 Abuf[3][2];

#define LOADA(kb_, s_)                                                         \
  {                                                                            \
    Abuf[s_][0] = *reinterpret_cast<const bf16x8*>(fl + ((ga0    ) * 16 + (kb_)) * 512); \
    Abuf[s_][1] = *reinterpret_cast<const bf16x8*>(fl + ((ga0 + 1) * 16 + (kb_)) * 512); \
  }

#define STEP(kb_, s_)                                                          \
  {                                                                            \
    const int kbb_ = (kb_) ^ 4;                                                \
    bf16x8 B0 = *reinterpret_cast<const bf16x8*>(bl + ((hb0    ) * 16 + kbb_) * 512); \
    bf16x8 B1 = *reinterpret_cast<const bf16x8*>(bl + ((hb0 + 1) * 16 + kbb_) * 512); \
    acc[0][0] = __builtin_amdgcn_mfma_f32_16x16x32_bf16(Abuf[s_][0], B0, acc[0][0], 0, 0, 0); \
    acc[0][1] = __builtin_amdgcn_mfma_f32_16x16x32_bf16(Abuf[s_][0], B1, acc[0][1], 0, 0, 0); \
    acc[1][0] = __builtin_amdgcn_mfma_f32_16x16x32_bf16(Abuf[s_][1], B0, acc[1][0], 0, 0, 0); \
    acc[1][1] = __builtin_amdgcn_mfma_f32_16x16x32_bf16(Abuf[s_][1], B1, acc[1][1], 0, 0, 0); \
  }

  LOADA(0, 0);
  LOADA(1, 1);
  #pragma unroll
  for (int kb = 0; kb < 16; ++kb) {
    if (kb < 14) { LOADA(kb + 2, (kb + 2) % 3); }
    STEP(kb, kb % 3);
  }
#undef LOADA
#undef STEP

  // ---- epilogue: NT-Xent online merge per output row ----
  const int ndup = min(dupcnt[0], DCAP);
  int ljv[2]; float qjv[2]; int fjv[2]; int gjv[2];
  #pragma unroll
  for (int fb = 0; fb < 2; ++fb) {
    const int gj = j0 + wc * 32 + fb * 16 + c0;
    const int lab = labels[gj];
    ljv[fb] = (msk[gj] == 1 && lab >= 0) ? lab : -1;
    qjv[fb] = qv[gj];
    fjv[fb] = rowflag[gj];
    gjv[fb] = gj;
  }
  #pragma unroll
  for (int fa = 0; fa < 2; ++fa) {
    const int ibase = i0 + wr * 32 + fa * 16 + gq * 4;
    int li4[4], mi4[4], fi4[4]; float qi4[4];
    *reinterpret_cast<int4*>(li4)   = *reinterpret_cast<const int4*>(labels + ibase);
    *reinterpret_cast<int4*>(mi4)   = *reinterpret_cast<const int4*>(msk + ibase);
    *reinterpret_cast<int4*>(fi4)   = *reinterpret_cast<const int4*>(rowflag + ibase);
    *reinterpret_cast<float4*>(qi4) = *reinterpret_cast<const float4*>(qv + ibase);
    #pragma unroll
    for (int r = 0; r < 4; ++r) {
      const int gi = ibase + r;
      const int li = (mi4[r] == 1 && li4[r] >= 0) ? li4[r] : -1;
      float m = -INFINITY, n = 0.f, d = 0.f, c = 0.f;
      if (li >= 0) {
        #pragma unroll
        for (int fb = 0; fb < 2; ++fb) {
          const int lj = ljv[fb];
          bool inc = (lj >= 0) && (gi != gjv[fb]);
          if (inc && fi4[r] && fjv[fb]) {
            int plo = min(gi, gjv[fb]), phi = max(gi, gjv[fb]);
            for (int e = 0; e < ndup; ++e) {
              int2 p = duplist[e];
              if (p.x == plo && p.y == phi) { inc = false; break; }
            }
          }
          if (inc) {
            float S = acc[fa][fb][r];
            float l = 64.0f - 0.25f * (qi4[r] + qjv[fb] + S);
            float w = (li == lj) ? 1.0f : 0.0f;
            mergeState(m, n, d, l, w, 1.0f);
            c += w;
          }
        }
      }
      #pragma unroll
      for (int o = 1; o < 16; o <<= 1) {
        float m2 = __shfl_xor(m, o);
        float n2 = __shfl_xor(n, o);
        float d2 = __shfl_xor(d, o);
        float c2 = __shfl_xor(c, o);
        mergeState(m, n, d, m2, n2, d2);
        c += c2;
      }
      if (c0 == 0)
        ipart[(size_t)(bj * 2 + wc) * NROWS + gi] = make_float4(m, n, d, c);
    }
  }
}

// ---------------------------------------------------------------------------
// k3: merge 64 j-slices per row, per-block sums, then device-scope atomic
// accumulate + ticket; last of 8 blocks writes the final scalar.
// gsum[0]=L, gsum[1]=C, gsum[2]=ticket (all cleared by k1m).
// ---------------------------------------------------------------------------
__global__ __launch_bounds__(256) void k3(const float4* __restrict__ ipart,
                                          float* __restrict__ gsum,
                                          float* __restrict__ out)
{
  const int r = blockIdx.x * 256 + threadIdx.x;
  float m = -INFINITY, n = 0.f, d = 0.f, c = 0.f;
  #pragma unroll 8
  for (int js = 0; js < 64; ++js) {
    float4 p = ipart[(size_t)js * NROWS + r];
    mergeState(m, n, d, p.x, p.y, p.z);
    c += p.w;
  }
  float lf = 0.f, ns = 0.f;
  if (c > 0.f) {
    lf = log2f(d) - log2f(n) + log2f(c);
    ns = 1.f;
  }
  #pragma unroll
  for (int o = 32; o; o >>= 1) {
    lf += __shfl_down(lf, o);
    ns += __shfl_down(ns, o);
  }
  __shared__ float sl[4], sn[4];
  const int wid = threadIdx.x >> 6;
  if ((threadIdx.x & 63) == 0) { sl[wid] = lf; sn[wid] = ns; }
  __syncthreads();
  if (threadIdx.x == 0) {
    float L = sl[0] + sl[1] + sl[2] + sl[3];
    float C = sn[0] + sn[1] + sn[2] + sn[3];
    atomicAdd(&gsum[0], L);
    atomicAdd(&gsum[1], C);
    __threadfence();
    unsigned int tk = atomicAdd(reinterpret_cast<unsigned int*>(gsum + 2), 1u);
    if (tk == 7u) {
      float Lt = atomicAdd(&gsum[0], 0.f);
      float Ct = atomicAdd(&gsum[1], 0.f);
      out[0] = Lt / fmaxf(Ct, 1.0f);
    }
  }
}

// ---------------------------------------------------------------------------
extern "C" void kernel_launch(void* const* d_in, const int* in_sizes, int n_in,
                              void* d_out, int out_size, void* d_ws, size_t ws_size,
                              hipStream_t stream) {
  const float* E   = (const float*)d_in[0];
  const int*   tid = (const int*)d_in[1];
  const int*   msk = (const int*)d_in[2];
  const float* Wmu = (const float*)d_in[3];
  const float* bmu = (const float*)d_in[4];
  const float* Wsg = (const float*)d_in[5];
  const float* bsg = (const float*)d_in[6];

  unsigned char* w = (unsigned char*)d_ws;
  unsigned short* Ftl  = (unsigned short*)w;  w += (size_t)NROWS * FEAT * 2;   // 2 MB
  float* Cpart         = (float*)w;           w += (size_t)4 * NROWS * 256 * 4; // 8 MB
  float* qv            = (float*)w;           w += (size_t)NROWS * 4;
  unsigned long long* tab = (unsigned long long*)w; w += (size_t)TSLOTS * 8;   // 64 KB
  int* rowflag         = (int*)w;             w += (size_t)NROWS * 4;
  int* dupcnt          = (int*)w;             w += 256;
  float* gsum          = (float*)w;           w += 256;
  int2* duplist        = (int2*)w;            w += (size_t)DCAP * 8;
  float4* ipart        = (float4*)w;          w += (size_t)64 * NROWS * 16;    // 2 MB

  k1m<<<256, 256, 0, stream>>>(E, Wmu, Wsg, Cpart, tab, rowflag, dupcnt, gsum);
  k1e<<<128, 256, 0, stream>>>(Cpart, bmu, bsg, Ftl, qv,
                               tab, rowflag, dupcnt, duplist);
  k2_mfma<<<512, 512, 0, stream>>>(Ftl, qv, tid, msk, rowflag,
                                   dupcnt, duplist, ipart);
  k3<<<8, 256, 0, stream>>>(ipart, gsum, (float*)d_out);
}